// Round 3
// baseline (169.235 us; speedup 1.0000x reference)
//
#include <hip/hip_runtime.h>
#include <hip/hip_bf16.h>

typedef __attribute__((ext_vector_type(8))) short short8;
typedef __attribute__((ext_vector_type(4))) float f32x4;

#define NPROTO 64
#define DIM    512
#define TAU_INV 5.0f

__device__ __forceinline__ unsigned short f2bf(float f) {
    union { float f; unsigned int u; } v; v.f = f;
    unsigned int r = v.u + 0x7FFFu + ((v.u >> 16) & 1u);  // round-to-nearest-even
    return (unsigned short)(r >> 16);
}

// ---------------------------------------------------------------------------
// Prep: p_norm (normalized protos, bf16, [64][512]) and protos^T (raw, bf16,
// [512][64]).
// ---------------------------------------------------------------------------
__global__ void pb_prep(const float* __restrict__ protos,
                        unsigned short* __restrict__ pnorm,
                        unsigned short* __restrict__ protosT) {
    const int k    = blockIdx.x;
    const int lane = threadIdx.x;
    const float* row = protos + k * DIM;
    float x[8];
    float ss = 0.0f;
#pragma unroll
    for (int j = 0; j < 8; ++j) {
        x[j] = row[lane * 8 + j];
        ss += x[j] * x[j];
    }
#pragma unroll
    for (int m = 1; m < 64; m <<= 1) ss += __shfl_xor(ss, m, 64);
    const float s = 1.0f / fmaxf(sqrtf(ss), 1e-12f);
    short8 pn;
#pragma unroll
    for (int j = 0; j < 8; ++j) pn[j] = (short)f2bf(x[j] * s);
    *reinterpret_cast<short8*>(pnorm + k * DIM + lane * 8) = pn;
#pragma unroll
    for (int j = 0; j < 8; ++j)
        protosT[(lane * 8 + j) * NPROTO + k] = f2bf(x[j]);
}

// ---------------------------------------------------------------------------
// Main v3: A staged via global_load_lds into a wave-private 4-deep LDS
// pipeline (no barriers in K-loop; counted inline-asm vmcnt). B (pnorm)
// register-prefetched 3 steps ahead in the SAME issue group as the DMAs so
// the in-order vmcnt FIFO never forces a drain: group = 4 DMA + 4 B loads,
// steady-state wait = vmcnt(24) (3 groups in flight).
// LDS A layout: [step&3][wave][row 0..31][granule16B], granule pre-swizzled
// (slot = j ^ (row&7)) via the per-lane GLOBAL source address (m173 pattern).
// ---------------------------------------------------------------------------
__global__ __launch_bounds__(256, 2) void pb_main(
    const float* __restrict__ seg,
    const unsigned short* __restrict__ pnorm,    // [64][512] bf16
    const unsigned short* __restrict__ protosT,  // [512][64] bf16
    float* __restrict__ out_pat,                 // [N][512]
    float* __restrict__ out_w,                   // [N][64]
    float* __restrict__ out_log) {               // [N][64]

    __shared__ char bufA[4 * 4 * 4096];                   // 64KB: [step&3][wave][4KB]
    __shared__ unsigned short wbuf_all[4 * 2 * 16 * 64];  // 16KB

    const int wid  = (int)(threadIdx.x >> 6);
    const int lane = (int)(threadIdx.x & 63);
    const int g    = lane >> 4;
    const int r16  = lane & 15;
    const long n0  = ((long)blockIdx.x * 4 + wid) * 32;  // wave's first row

    // ---- staging source map: instr i covers rows i*8 + (lane>>3);
    //      granule content j = (lane&7) ^ (row&7) lands at LDS slot lane&7.
    const int sr = lane >> 3;
    const int sj = (lane & 7) ^ (sr & 7);
    const float* sbase = seg + (n0 + sr) * DIM + sj * 4;
    char* wavebuf = bufA + wid * 4096;

#define STAGE(KT) do {                                                         \
    char* _d = wavebuf + ((KT) & 3) * 16384;                                   \
    const float* _s = sbase + (KT) * 32;                                       \
    _Pragma("unroll")                                                          \
    for (int _i = 0; _i < 4; ++_i)                                             \
        __builtin_amdgcn_global_load_lds(                                      \
            (const __attribute__((address_space(1))) void*)(_s + _i * 8 * DIM),\
            (__attribute__((address_space(3))) void*)(_d + _i * 1024),         \
            16, 0, 0);                                                         \
} while (0)

    short8 breg[4][4];
#define BLOAD(KT) do {                                                         \
    _Pragma("unroll")                                                          \
    for (int _c = 0; _c < 4; ++_c)                                             \
        breg[(KT) & 3][_c] = *reinterpret_cast<const short8*>(                 \
            pnorm + (_c * 16 + r16) * DIM + g * 8 + (KT) * 32);                \
} while (0)

    f32x4 acc0[4] = {}, acc1[4] = {};
    float ss0 = 0.0f, ss1 = 0.0f;

    // prologue: 3 groups in flight
    STAGE(0); BLOAD(0);
    STAGE(1); BLOAD(1);
    STAGE(2); BLOAD(2);

    const int ra  = r16 & 7;                 // swizzle key (same for both frags)
    const int s0a = ((2 * g)     ^ ra) * 16;
    const int s0b = ((2 * g + 1) ^ ra) * 16;

#pragma unroll
    for (int kt = 0; kt < 16; ++kt) {
        if (kt + 3 < 16) { STAGE(kt + 3); BLOAD(kt + 3); }
        // wait: group kt done; groups kt+1..kt+3 (8 ops each) may stay in flight
        if (kt <= 12)      asm volatile("s_waitcnt vmcnt(24)" ::: "memory");
        else if (kt == 13) asm volatile("s_waitcnt vmcnt(16)" ::: "memory");
        else if (kt == 14) asm volatile("s_waitcnt vmcnt(8)"  ::: "memory");
        else               asm volatile("s_waitcnt vmcnt(0)"  ::: "memory");
        __builtin_amdgcn_sched_barrier(0);

        char* sb = wavebuf + (kt & 3) * 16384;
        const f32x4 a00 = *reinterpret_cast<const f32x4*>(sb + r16 * 128 + s0a);
        const f32x4 a01 = *reinterpret_cast<const f32x4*>(sb + r16 * 128 + s0b);
        const f32x4 a10 = *reinterpret_cast<const f32x4*>(sb + (16 + r16) * 128 + s0a);
        const f32x4 a11 = *reinterpret_cast<const f32x4*>(sb + (16 + r16) * 128 + s0b);

        short8 af0, af1;
#pragma unroll
        for (int j = 0; j < 4; ++j) {
            ss0 += a00[j] * a00[j] + a01[j] * a01[j];
            ss1 += a10[j] * a10[j] + a11[j] * a11[j];
            af0[j] = (short)f2bf(a00[j]); af0[j + 4] = (short)f2bf(a01[j]);
            af1[j] = (short)f2bf(a10[j]); af1[j + 4] = (short)f2bf(a11[j]);
        }
#pragma unroll
        for (int c = 0; c < 4; ++c) {
            acc0[c] = __builtin_amdgcn_mfma_f32_16x16x32_bf16(af0, breg[kt & 3][c], acc0[c], 0, 0, 0);
            acc1[c] = __builtin_amdgcn_mfma_f32_16x16x32_bf16(af1, breg[kt & 3][c], acc1[c], 0, 0, 0);
        }
    }

    // ---- per-row 1/|z|, redistribute to D-layout rows --------------------
    ss0 += __shfl_xor(ss0, 16, 64); ss0 += __shfl_xor(ss0, 32, 64);
    ss1 += __shfl_xor(ss1, 16, 64); ss1 += __shfl_xor(ss1, 32, 64);
    const float sco0 = TAU_INV / fmaxf(sqrtf(ss0), 1e-12f);
    const float sco1 = TAU_INV / fmaxf(sqrtf(ss1), 1e-12f);
    float sc0[4], sc1[4];
#pragma unroll
    for (int q = 0; q < 4; ++q) {
        sc0[q] = __shfl(sco0, g * 4 + q, 64);
        sc1[q] = __shfl(sco1, g * 4 + q, 64);
    }

    float lg0[4][4], lg1[4][4];
#pragma unroll
    for (int c = 0; c < 4; ++c)
#pragma unroll
        for (int q = 0; q < 4; ++q) {
            lg0[c][q] = acc0[c][q] * sc0[q];
            lg1[c][q] = acc1[c][q] * sc1[q];
            out_log[(n0 + g * 4 + q) * NPROTO + c * 16 + r16]      = lg0[c][q];
            out_log[(n0 + 16 + g * 4 + q) * NPROTO + c * 16 + r16] = lg1[c][q];
        }

    // ---- softmax over 64 protos per row ----------------------------------
    float w0[4][4], w1[4][4];
#pragma unroll
    for (int q = 0; q < 4; ++q) {
        float mx0 = fmaxf(fmaxf(lg0[0][q], lg0[1][q]), fmaxf(lg0[2][q], lg0[3][q]));
        float mx1 = fmaxf(fmaxf(lg1[0][q], lg1[1][q]), fmaxf(lg1[2][q], lg1[3][q]));
#pragma unroll
        for (int msk = 1; msk < 16; msk <<= 1) {
            mx0 = fmaxf(mx0, __shfl_xor(mx0, msk, 64));
            mx1 = fmaxf(mx1, __shfl_xor(mx1, msk, 64));
        }
        float e0[4], e1[4], sum0 = 0.0f, sum1 = 0.0f;
#pragma unroll
        for (int c = 0; c < 4; ++c) {
            e0[c] = __expf(lg0[c][q] - mx0); sum0 += e0[c];
            e1[c] = __expf(lg1[c][q] - mx1); sum1 += e1[c];
        }
#pragma unroll
        for (int msk = 1; msk < 16; msk <<= 1) {
            sum0 += __shfl_xor(sum0, msk, 64);
            sum1 += __shfl_xor(sum1, msk, 64);
        }
        const float i0 = 1.0f / sum0, i1 = 1.0f / sum1;
#pragma unroll
        for (int c = 0; c < 4; ++c) { w0[c][q] = e0[c] * i0; w1[c][q] = e1[c] * i1; }
    }

    // ---- store w + LDS transpose (D-layout -> A-layout), XOR swizzled -----
    unsigned short* wb0 = wbuf_all + (wid * 2 + 0) * (16 * 64);
    unsigned short* wb1 = wbuf_all + (wid * 2 + 1) * (16 * 64);
#pragma unroll
    for (int c = 0; c < 4; ++c)
#pragma unroll
        for (int q = 0; q < 4; ++q) {
            out_w[(n0 + g * 4 + q) * NPROTO + c * 16 + r16]      = w0[c][q];
            out_w[(n0 + 16 + g * 4 + q) * NPROTO + c * 16 + r16] = w1[c][q];
            const int row  = g * 4 + q;
            const int col  = c * 16 + r16;
            const int byte = (row * 128 + col * 2) ^ ((row & 7) << 4);
            *reinterpret_cast<unsigned short*>(reinterpret_cast<char*>(wb0) + byte) = f2bf(w0[c][q]);
            *reinterpret_cast<unsigned short*>(reinterpret_cast<char*>(wb1) + byte) = f2bf(w1[c][q]);
        }

    __syncthreads();

    short8 wa[2][2];
    {
        const int row = r16;
        const int b0 = (row * 128 + g * 16)      ^ ((row & 7) << 4);
        const int b1 = (row * 128 + g * 16 + 64) ^ ((row & 7) << 4);
        wa[0][0] = *reinterpret_cast<const short8*>(reinterpret_cast<char*>(wb0) + b0);
        wa[0][1] = *reinterpret_cast<const short8*>(reinterpret_cast<char*>(wb0) + b1);
        wa[1][0] = *reinterpret_cast<const short8*>(reinterpret_cast<char*>(wb1) + b0);
        wa[1][1] = *reinterpret_cast<const short8*>(reinterpret_cast<char*>(wb1) + b1);
    }

    // ---- pattern = w · protos : K=64, 32 col-tiles, 2-deep B prefetch -----
    short8 pbuf[2][2];
    const unsigned short* btile = protosT + r16 * NPROTO + g * 8;
    pbuf[0][0] = *reinterpret_cast<const short8*>(btile);
    pbuf[0][1] = *reinterpret_cast<const short8*>(btile + 32);
#pragma unroll
    for (int cp = 0; cp < 32; ++cp) {
        if (cp < 31) {
            const unsigned short* bn = btile + (cp + 1) * 16 * NPROTO;
            pbuf[(cp + 1) & 1][0] = *reinterpret_cast<const short8*>(bn);
            pbuf[(cp + 1) & 1][1] = *reinterpret_cast<const short8*>(bn + 32);
        }
        f32x4 p0 = {}, p1 = {};
        p0 = __builtin_amdgcn_mfma_f32_16x16x32_bf16(wa[0][0], pbuf[cp & 1][0], p0, 0, 0, 0);
        p0 = __builtin_amdgcn_mfma_f32_16x16x32_bf16(wa[0][1], pbuf[cp & 1][1], p0, 0, 0, 0);
        p1 = __builtin_amdgcn_mfma_f32_16x16x32_bf16(wa[1][0], pbuf[cp & 1][0], p1, 0, 0, 0);
        p1 = __builtin_amdgcn_mfma_f32_16x16x32_bf16(wa[1][1], pbuf[cp & 1][1], p1, 0, 0, 0);
#pragma unroll
        for (int q = 0; q < 4; ++q) {
            out_pat[(n0 + g * 4 + q) * DIM + cp * 16 + r16]      = p0[q];
            out_pat[(n0 + 16 + g * 4 + q) * DIM + cp * 16 + r16] = p1[q];
        }
    }
#undef STAGE
#undef BLOAD
}

extern "C" void kernel_launch(void* const* d_in, const int* in_sizes, int n_in,
                              void* d_out, int out_size, void* d_ws, size_t ws_size,
                              hipStream_t stream) {
    const float* seg    = (const float*)d_in[0];
    const float* protos = (const float*)d_in[1];
    const int N = in_sizes[0] / DIM;  // 131072

    float* out     = (float*)d_out;
    float* out_pat = out;
    float* out_w   = out_pat + (size_t)N * DIM;
    float* out_log = out_w + (size_t)N * NPROTO;

    unsigned short* pnorm   = (unsigned short*)d_ws;
    unsigned short* protosT = pnorm + NPROTO * DIM;

    pb_prep<<<NPROTO, 64, 0, stream>>>(protos, pnorm, protosT);
    pb_main<<<N / 128, 256, 0, stream>>>(seg, pnorm, protosT, out_pat, out_w, out_log);
}